// Round 2
// baseline (628.360 us; speedup 1.0000x reference)
//
#include <hip/hip_runtime.h>

// MS-Deformable Attention, MI355X gfx950.
// Pipeline: prep(weights->bf16,[N][K]) ; v=value@Wv (bf16 MFMA, out bf16)
//           p=query@[Woff|Wattn] (bf16 MFMA, out fp32, N padded to 128)
//           sampling (bilinear gather from bf16 v, out bf16)
//           out = samp@Wo + b + query (bf16 MFMA, fp32 out)
// R2: gemm was latency-bound (MfmaUtil 3.9%, VALUBusy 3.3%, occ 25%).
//     -> software-pipelined reg prefetch, BK=64 (4 iters), pad 68 (0 conflicts).
// R3: (a) GEMM blocks now cover full N in one block (8 waves, 512 thr,
//         128xBN tile) -> A panels fetched ONCE (was twice for N=256),
//         half the blocks -> half the latency-exposed rounds per CU.
//     (b) sample_k __launch_bounds__(256,8): force VGPR<=64 so the
//         gather-latency-bound kernel gets 8 waves/SIMD (was 4, occ 28%).
// R4: resubmit of R3 — previous round died on container acquire (infra),
//     no counters produced; kernel unchanged.

typedef float  f4  __attribute__((ext_vector_type(4)));
typedef float  fx4 __attribute__((ext_vector_type(4)));
typedef short  s8  __attribute__((ext_vector_type(8)));
typedef short  s4  __attribute__((ext_vector_type(4)));

#define KDIM    256
#define NVPIX   40000
#define GH      200
#define GW      200
#define LDP     68          // LDS row pitch in shorts: 64 data + 4 pad -> conflict-free

__device__ __forceinline__ short f2bf(float f) {
  union { float f; unsigned u; } v; v.f = f;
  unsigned r = v.u + 0x7fffu + ((v.u >> 16) & 1u);   // round-to-nearest-even
  return (short)(r >> 16);
}
__device__ __forceinline__ float bf2f(unsigned short h) {
  union { unsigned u; float f; } v; v.u = ((unsigned)h) << 16; return v.f;
}

// ---------------------------------------------------------------- prep ----
__global__ void prep_k(const float* __restrict__ Wv, const float* __restrict__ Wo,
                       const float* __restrict__ Woff, const float* __restrict__ Wattn,
                       const float* __restrict__ boff, const float* __restrict__ battn,
                       unsigned short* __restrict__ Wv_t, unsigned short* __restrict__ Wo_t,
                       unsigned short* __restrict__ Wp_t, float* __restrict__ bp)
{
  int i = blockIdx.x * 256 + threadIdx.x;
  if (i < 65536) {
    int n = i >> 8, k = i & 255;
    Wv_t[i] = (unsigned short)f2bf(Wv[k * 256 + n]);
  } else if (i < 131072) {
    int j = i - 65536; int n = j >> 8, k = j & 255;
    Wo_t[j] = (unsigned short)f2bf(Wo[k * 256 + n]);
  } else if (i < 163840) {
    int j = i - 131072; int n = j >> 8, k = j & 255;
    float val = (n < 64) ? Woff[k * 64 + n] : ((n < 96) ? Wattn[k * 32 + (n - 64)] : 0.f);
    Wp_t[j] = (unsigned short)f2bf(val);
  } else if (i < 163968) {
    int j = i - 163840;
    bp[j] = (j < 64) ? boff[j] : ((j < 96) ? battn[j - 64] : 0.f);
  }
}

// ---------------------------------------------------------------- GEMM ----
// C[M,BN] = A[M,K=256] * B^T (Bt [BN][K] bf16) + bias (+resid). 128xBN tile
// (BN = full output width: 256 or 128), BK=64 (4 k-iters), 8 waves.
// BN=256: wave grid 2x4, 64x64 quadrant each, acc[4][4].
// BN=128: wave grid 2x4, 64x32 quadrant each, acc[4][2].
// Register-prefetch pipeline: next tile's global loads are issued BEFORE the
// MFMA section so HBM latency overlaps MFMAs + ds_reads; waitcnt lands at
// next iter's ds_write. A panels are read exactly once from HBM.
template<int ABF, int CBF, int RES, int BN>
__global__ __launch_bounds__(512)
void gemm_k(const void* __restrict__ Ap, const unsigned short* __restrict__ Bt,
            const float* __restrict__ bias, const float* __restrict__ resid,
            void* __restrict__ Cp)
{
  constexpr int ACCJ = BN / 64;        // 4 (BN=256) or 2 (BN=128)
  constexpr int WN   = BN / 4;         // per-wave N extent: 64 or 32
  __shared__ short As[128 * LDP];
  __shared__ short Bs[BN * LDP];
  const int t  = threadIdx.x;
  const int m0 = blockIdx.x * 128;
  const int lane = t & 63;
  const int w  = t >> 6;               // 0..7
  const int wm = (w >> 2) * 64;        // 0,64
  const int wn = (w & 3) * WN;
  const int fr = lane & 15;
  const int quad = lane >> 4;

  fx4 acc[4][ACCJ];
  #pragma unroll
  for (int i = 0; i < 4; i++)
    #pragma unroll
    for (int j = 0; j < ACCJ; j++) { fx4 z = {0.f, 0.f, 0.f, 0.f}; acc[i][j] = z; }

  f4 pa[4];      // ABF=0 prefetch: 128x64 f32 tile = 2048 f4, 4 per thread
  s8 pa8[2];     // ABF=1 prefetch: 128x64 bf16 tile = 1024 s8, 2 per thread
  s8 pb[ACCJ];   // B prefetch: BN x 64 bf16 = BN*8 s8, BN/64 per thread

  auto loadA = [&](int k0) {
    if (ABF) {
      const unsigned short* base = (const unsigned short*)Ap + (size_t)m0 * KDIM + k0;
      #pragma unroll
      for (int j = 0; j < 2; j++) {
        int id = t + j * 512;                   // coalesced
        int row = id >> 3, kp = (id & 7) * 8;
        pa8[j] = *(const s8*)(base + (size_t)row * KDIM + kp);
      }
    } else {
      const float* base = (const float*)Ap + (size_t)m0 * KDIM + k0;
      #pragma unroll
      for (int j = 0; j < 4; j++) {
        int id = t + j * 512;                   // coalesced
        int row = id >> 4, kp = (id & 15) * 4;
        pa[j] = *(const f4*)(base + (size_t)row * KDIM + kp);
      }
    }
  };
  auto loadB = [&](int k0) {
    const unsigned short* base = Bt + k0;
    #pragma unroll
    for (int j = 0; j < ACCJ; j++) {
      int id = t + j * 512;
      int row = id >> 3, kp = (id & 7) * 8;
      pb[j] = *(const s8*)(base + (size_t)row * KDIM + kp);
    }
  };
  auto storeAB = [&]() {
    if (ABF) {
      #pragma unroll
      for (int j = 0; j < 2; j++) {
        int id = t + j * 512;
        int row = id >> 3, kp = (id & 7) * 8;
        *(s8*)(&As[row * LDP + kp]) = pa8[j];
      }
    } else {
      #pragma unroll
      for (int j = 0; j < 4; j++) {
        int id = t + j * 512;
        int row = id >> 4, kp = (id & 15) * 4;
        s4 c;
        #pragma unroll
        for (int e = 0; e < 4; e++) c[e] = f2bf(pa[j][e]);
        *(s4*)(&As[row * LDP + kp]) = c;        // ds_write_b64, conflict-free
      }
    }
    #pragma unroll
    for (int j = 0; j < ACCJ; j++) {
      int id = t + j * 512;
      int row = id >> 3, kp = (id & 7) * 8;
      *(s8*)(&Bs[row * LDP + kp]) = pb[j];      // ds_write_b128, conflict-free
    }
  };

  loadA(0); loadB(0);
  #pragma unroll
  for (int it = 0; it < 4; ++it) {
    __syncthreads();            // prev-iter LDS reads complete
    storeAB();
    __syncthreads();
    if (it < 3) { loadA((it + 1) * 64); loadB((it + 1) * 64); }  // prefetch next
    #pragma unroll
    for (int kk = 0; kk < 2; kk++) {
      s8 afr[4], bfr[ACCJ];
      #pragma unroll
      for (int i = 0; i < 4; i++)
        afr[i] = *(const s8*)(&As[(wm + i * 16 + fr) * LDP + kk * 32 + quad * 8]);
      #pragma unroll
      for (int j = 0; j < ACCJ; j++)
        bfr[j] = *(const s8*)(&Bs[(wn + j * 16 + fr) * LDP + kk * 32 + quad * 8]);
      #pragma unroll
      for (int i = 0; i < 4; i++)
        #pragma unroll
        for (int j = 0; j < ACCJ; j++)
          acc[i][j] = __builtin_amdgcn_mfma_f32_16x16x32_bf16(afr[i], bfr[j], acc[i][j], 0, 0, 0);
    }
  }

  // Epilogue: C/D layout col=lane&15, row=quad*4+reg (verified m89/m91).
  #pragma unroll
  for (int i = 0; i < 4; i++) {
    const int mbase = m0 + wm + i * 16 + quad * 4;
    #pragma unroll
    for (int j = 0; j < ACCJ; j++) {
      const int n = wn + j * 16 + fr;
      const float bn = bias[n];
      #pragma unroll
      for (int r = 0; r < 4; r++) {
        const size_t m = (size_t)(mbase + r);
        float v = acc[i][j][r] + bn;
        if (RES) v += resid[m * (size_t)BN + n];
        if (CBF) ((unsigned short*)Cp)[m * (size_t)BN + n] = (unsigned short)f2bf(v);
        else     ((float*)Cp)[m * (size_t)BN + n] = v;
      }
    }
  }
}

// ------------------------------------------------------------- sampling ----
// 8 queries per block. Thread t: query qi=t>>5, head h=(t>>2)&7, dim-group
// dg=t&3 (8 consecutive dims -> one dwordx4 per corner). Validity folded
// into weights; loads unconditional with clamped indices.
// R3: launch_bounds(256,8) caps VGPR at 64 -> 8 waves/SIMD for this
// gather-latency-bound kernel (was 72 VGPR -> 4 waves/SIMD, occ 28%).
__global__ __launch_bounds__(256, 8)
void sample_k(const unsigned short* __restrict__ v, const float* __restrict__ p,
              const float* __restrict__ ref, unsigned short* __restrict__ o)
{
  const int t  = threadIdx.x;
  const int q0 = blockIdx.x * 8;
  __shared__ float sp[8][128];
  __shared__ float sref[16];
  {
    const float* pb = p + (size_t)q0 * 128;
    #pragma unroll
    for (int j = 0; j < 4; j++) {
      int i = t + j * 256;
      sp[i >> 7][i & 127] = pb[i];
    }
    if (t < 16) sref[t] = ref[(size_t)q0 * 2 + t];
  }
  __syncthreads();

  const int qi = t >> 5;
  const int h  = (t >> 2) & 7;
  const int dg = t & 3;
  const int q  = q0 + qi;
  const int b  = (q >= 40000) ? 1 : 0;

  const float lg0 = sp[qi][64 + h * 4 + 0], lg1 = sp[qi][64 + h * 4 + 1];
  const float lg2 = sp[qi][64 + h * 4 + 2], lg3 = sp[qi][64 + h * 4 + 3];
  const float mx = fmaxf(fmaxf(lg0, lg1), fmaxf(lg2, lg3));
  const float e0 = __expf(lg0 - mx), e1 = __expf(lg1 - mx);
  const float e2 = __expf(lg2 - mx), e3 = __expf(lg3 - mx);
  const float inv = 1.f / (e0 + e1 + e2 + e3);
  const float aws[4] = {e0 * inv, e1 * inv, e2 * inv, e3 * inv};
  const float rx = sref[qi * 2], ry = sref[qi * 2 + 1];

  const unsigned short* vb = v + (size_t)b * NVPIX * 256;
  const int cbase = h * 32 + dg * 8;

  float acc[8];
  #pragma unroll
  for (int e = 0; e < 8; e++) acc[e] = 0.f;

  #pragma unroll
  for (int pt = 0; pt < 4; ++pt) {
    const float ox = sp[qi][h * 8 + pt * 2], oy = sp[qi][h * 8 + pt * 2 + 1];
    // px = loc_x*W - 0.5 with loc_x = rx + ox/W  ->  rx*W + ox - 0.5
    const float px = rx * 200.f + ox - 0.5f;
    const float py = ry * 200.f + oy - 0.5f;
    const float x0f = floorf(px), y0f = floorf(py);
    const int ix = (int)x0f, iy = (int)y0f;
    const float fx = px - x0f, fy = py - y0f;
    const float a = aws[pt];
    const float vx0 = (ix >= 0 && ix < GW) ? 1.f : 0.f;
    const float vx1 = (ix + 1 >= 0 && ix + 1 < GW) ? 1.f : 0.f;
    const float vy0 = (iy >= 0 && iy < GH) ? 1.f : 0.f;
    const float vy1 = (iy + 1 >= 0 && iy + 1 < GH) ? 1.f : 0.f;
    const float w00 = a * (1.f - fx) * (1.f - fy) * vx0 * vy0;
    const float w01 = a * fx * (1.f - fy) * vx1 * vy0;
    const float w10 = a * (1.f - fx) * fy * vx0 * vy1;
    const float w11 = a * fx * fy * vx1 * vy1;
    const int ix0c = min(max(ix, 0), GW - 1);
    const int ix1c = min(max(ix + 1, 0), GW - 1);
    const int iy0c = min(max(iy, 0), GH - 1);
    const int iy1c = min(max(iy + 1, 0), GH - 1);
    const int r0 = iy0c * (GW * 256) + cbase;
    const int r1 = iy1c * (GW * 256) + cbase;
    s8 g00 = *(const s8*)(vb + r0 + ix0c * 256);
    s8 g01 = *(const s8*)(vb + r0 + ix1c * 256);
    s8 g10 = *(const s8*)(vb + r1 + ix0c * 256);
    s8 g11 = *(const s8*)(vb + r1 + ix1c * 256);
    #pragma unroll
    for (int e = 0; e < 8; e++) {
      acc[e] += w00 * bf2f((unsigned short)g00[e]) + w01 * bf2f((unsigned short)g01[e])
              + w10 * bf2f((unsigned short)g10[e]) + w11 * bf2f((unsigned short)g11[e]);
    }
  }

  s8 res;
  #pragma unroll
  for (int e = 0; e < 8; e++) res[e] = f2bf(acc[e]);
  *(s8*)(o + (size_t)q * 256 + cbase) = res;
}

// --------------------------------------------------------------- launch ----
extern "C" void kernel_launch(void* const* d_in, const int* in_sizes, int n_in,
                              void* d_out, int out_size, void* d_ws, size_t ws_size,
                              hipStream_t stream)
{
  const float* query = (const float*)d_in[0];
  const float* value = (const float*)d_in[1];
  const float* refp  = (const float*)d_in[2];
  // d_in[3] spatial_shapes: compile-time (200,200)
  const float* Wv    = (const float*)d_in[4];
  const float* bv    = (const float*)d_in[5];
  const float* Woff  = (const float*)d_in[6];
  const float* boff  = (const float*)d_in[7];
  const float* Wattn = (const float*)d_in[8];
  const float* battn = (const float*)d_in[9];
  const float* Wo    = (const float*)d_in[10];
  const float* bo    = (const float*)d_in[11];

  char* ws = (char*)d_ws;
  unsigned short* ws_v = (unsigned short*)ws;                  // 80000*256 bf16 = 40.96 MB
  float*          ws_p = (float*)(ws + 40960000);              // 80000*128 f32  = 40.96 MB
  unsigned short* ws_o = (unsigned short*)(ws + 81920000);     // 80000*256 bf16 = 40.96 MB
  unsigned short* Wv_t = (unsigned short*)(ws + 122880000);    // 256*256 bf16
  unsigned short* Wo_t = Wv_t + 65536;                         // 256*256 bf16
  unsigned short* Wp_t = Wo_t + 65536;                         // 128*256 bf16
  float*          bp   = (float*)(Wp_t + 32768);               // 128 f32

  hipLaunchKernelGGL(prep_k, dim3(641), dim3(256), 0, stream,
                     Wv, Wo, Woff, Wattn, boff, battn, Wv_t, Wo_t, Wp_t, bp);
  // v = value @ Wv + bv  -> bf16   (A read once: 128x256 tile per block)
  hipLaunchKernelGGL((gemm_k<0, 1, 0, 256>), dim3(625), dim3(512), 0, stream,
                     (const void*)value, Wv_t, bv, (const float*)nullptr, (void*)ws_v);
  // p = query @ [Woff|Wattn|0] + bp -> f32 (stride 128)
  hipLaunchKernelGGL((gemm_k<0, 0, 0, 128>), dim3(625), dim3(512), 0, stream,
                     (const void*)query, Wp_t, bp, (const float*)nullptr, (void*)ws_p);
  // sampling
  hipLaunchKernelGGL(sample_k, dim3(10000), dim3(256), 0, stream,
                     ws_v, ws_p, refp, ws_o);
  // out = samp @ Wo + bo + query -> f32
  hipLaunchKernelGGL((gemm_k<1, 0, 1, 256>), dim3(625), dim3(512), 0, stream,
                     (const void*)ws_o, Wo_t, bo, query, (void*)d_out);
}

// Round 3
// 341.366 us; speedup vs baseline: 1.8407x; 1.8407x over previous
//
#include <hip/hip_runtime.h>

// MS-Deformable Attention, MI355X gfx950.
// Pipeline: prep(weights->bf16,[N][K]) ; v=value@Wv (bf16 MFMA, out bf16)
//           p=query@[Woff|Wattn] (bf16 MFMA, out fp32, N padded to 128)
//           sampling (bilinear gather from bf16 v, out bf16)
//           out = samp@Wo + b + query (bf16 MFMA, fp32 out)
// R2: gemm was latency-bound -> software-pipelined reg prefetch, BK=64.
// R3: GEMM 8 waves/block, full-N tile (A read once). Neutral per R2 bench.
// R4: infra failure, resubmit.
// R5: sample_k post-mortem: __launch_bounds__(256,8) forced VGPR 72->32 ->
//     massive scratch spill (WRITE_SIZE 40->840MB, dur 66->338us). REVERTED.
//     New sample_k: (a) launch_bounds(256,4) (VGPR cap 128, no spill, same
//     4 waves/SIMD as 72-reg version); (b) phase-split: 256 threads compute
//     one (q,h,pt) weight/offset set each into LDS (4x less redundant VALU),
//     then all 16 gather loads issued back-to-back (16 in flight vs ~6-8);
//     (c) dword-pair bf16 unpack (1 VALU/elem).

typedef float  f4  __attribute__((ext_vector_type(4)));
typedef float  fx4 __attribute__((ext_vector_type(4)));
typedef short  s8  __attribute__((ext_vector_type(8)));
typedef short  s4  __attribute__((ext_vector_type(4)));
typedef int    i4  __attribute__((ext_vector_type(4)));
typedef unsigned int u4 __attribute__((ext_vector_type(4)));

#define KDIM    256
#define NVPIX   40000
#define GH      200
#define GW      200
#define LDP     68          // LDS row pitch in shorts: 64 data + 4 pad -> conflict-free

__device__ __forceinline__ short f2bf(float f) {
  union { float f; unsigned u; } v; v.f = f;
  unsigned r = v.u + 0x7fffu + ((v.u >> 16) & 1u);   // round-to-nearest-even
  return (short)(r >> 16);
}
__device__ __forceinline__ float bf2f(unsigned short h) {
  union { unsigned u; float f; } v; v.u = ((unsigned)h) << 16; return v.f;
}
__device__ __forceinline__ float asf(unsigned u) {
  union { unsigned u; float f; } v; v.u = u; return v.f;
}

// ---------------------------------------------------------------- prep ----
__global__ void prep_k(const float* __restrict__ Wv, const float* __restrict__ Wo,
                       const float* __restrict__ Woff, const float* __restrict__ Wattn,
                       const float* __restrict__ boff, const float* __restrict__ battn,
                       unsigned short* __restrict__ Wv_t, unsigned short* __restrict__ Wo_t,
                       unsigned short* __restrict__ Wp_t, float* __restrict__ bp)
{
  int i = blockIdx.x * 256 + threadIdx.x;
  if (i < 65536) {
    int n = i >> 8, k = i & 255;
    Wv_t[i] = (unsigned short)f2bf(Wv[k * 256 + n]);
  } else if (i < 131072) {
    int j = i - 65536; int n = j >> 8, k = j & 255;
    Wo_t[j] = (unsigned short)f2bf(Wo[k * 256 + n]);
  } else if (i < 163840) {
    int j = i - 131072; int n = j >> 8, k = j & 255;
    float val = (n < 64) ? Woff[k * 64 + n] : ((n < 96) ? Wattn[k * 32 + (n - 64)] : 0.f);
    Wp_t[j] = (unsigned short)f2bf(val);
  } else if (i < 163968) {
    int j = i - 163840;
    bp[j] = (j < 64) ? boff[j] : ((j < 96) ? battn[j - 64] : 0.f);
  }
}

// ---------------------------------------------------------------- GEMM ----
// C[M,BN] = A[M,K=256] * B^T (Bt [BN][K] bf16) + bias (+resid). 128xBN tile
// (BN = full output width: 256 or 128), BK=64 (4 k-iters), 8 waves.
template<int ABF, int CBF, int RES, int BN>
__global__ __launch_bounds__(512)
void gemm_k(const void* __restrict__ Ap, const unsigned short* __restrict__ Bt,
            const float* __restrict__ bias, const float* __restrict__ resid,
            void* __restrict__ Cp)
{
  constexpr int ACCJ = BN / 64;        // 4 (BN=256) or 2 (BN=128)
  constexpr int WN   = BN / 4;         // per-wave N extent: 64 or 32
  __shared__ short As[128 * LDP];
  __shared__ short Bs[BN * LDP];
  const int t  = threadIdx.x;
  const int m0 = blockIdx.x * 128;
  const int lane = t & 63;
  const int w  = t >> 6;               // 0..7
  const int wm = (w >> 2) * 64;        // 0,64
  const int wn = (w & 3) * WN;
  const int fr = lane & 15;
  const int quad = lane >> 4;

  fx4 acc[4][ACCJ];
  #pragma unroll
  for (int i = 0; i < 4; i++)
    #pragma unroll
    for (int j = 0; j < ACCJ; j++) { fx4 z = {0.f, 0.f, 0.f, 0.f}; acc[i][j] = z; }

  f4 pa[4];      // ABF=0 prefetch: 128x64 f32 tile = 2048 f4, 4 per thread
  s8 pa8[2];     // ABF=1 prefetch: 128x64 bf16 tile = 1024 s8, 2 per thread
  s8 pb[ACCJ];   // B prefetch: BN x 64 bf16 = BN*8 s8, BN/64 per thread

  auto loadA = [&](int k0) {
    if (ABF) {
      const unsigned short* base = (const unsigned short*)Ap + (size_t)m0 * KDIM + k0;
      #pragma unroll
      for (int j = 0; j < 2; j++) {
        int id = t + j * 512;                   // coalesced
        int row = id >> 3, kp = (id & 7) * 8;
        pa8[j] = *(const s8*)(base + (size_t)row * KDIM + kp);
      }
    } else {
      const float* base = (const float*)Ap + (size_t)m0 * KDIM + k0;
      #pragma unroll
      for (int j = 0; j < 4; j++) {
        int id = t + j * 512;                   // coalesced
        int row = id >> 4, kp = (id & 15) * 4;
        pa[j] = *(const f4*)(base + (size_t)row * KDIM + kp);
      }
    }
  };
  auto loadB = [&](int k0) {
    const unsigned short* base = Bt + k0;
    #pragma unroll
    for (int j = 0; j < ACCJ; j++) {
      int id = t + j * 512;
      int row = id >> 3, kp = (id & 7) * 8;
      pb[j] = *(const s8*)(base + (size_t)row * KDIM + kp);
    }
  };
  auto storeAB = [&]() {
    if (ABF) {
      #pragma unroll
      for (int j = 0; j < 2; j++) {
        int id = t + j * 512;
        int row = id >> 3, kp = (id & 7) * 8;
        *(s8*)(&As[row * LDP + kp]) = pa8[j];
      }
    } else {
      #pragma unroll
      for (int j = 0; j < 4; j++) {
        int id = t + j * 512;
        int row = id >> 4, kp = (id & 15) * 4;
        s4 c;
        #pragma unroll
        for (int e = 0; e < 4; e++) c[e] = f2bf(pa[j][e]);
        *(s4*)(&As[row * LDP + kp]) = c;        // ds_write_b64, conflict-free
      }
    }
    #pragma unroll
    for (int j = 0; j < ACCJ; j++) {
      int id = t + j * 512;
      int row = id >> 3, kp = (id & 7) * 8;
      *(s8*)(&Bs[row * LDP + kp]) = pb[j];      // ds_write_b128, conflict-free
    }
  };

  loadA(0); loadB(0);
  #pragma unroll
  for (int it = 0; it < 4; ++it) {
    __syncthreads();            // prev-iter LDS reads complete
    storeAB();
    __syncthreads();
    if (it < 3) { loadA((it + 1) * 64); loadB((it + 1) * 64); }  // prefetch next
    #pragma unroll
    for (int kk = 0; kk < 2; kk++) {
      s8 afr[4], bfr[ACCJ];
      #pragma unroll
      for (int i = 0; i < 4; i++)
        afr[i] = *(const s8*)(&As[(wm + i * 16 + fr) * LDP + kk * 32 + quad * 8]);
      #pragma unroll
      for (int j = 0; j < ACCJ; j++)
        bfr[j] = *(const s8*)(&Bs[(wn + j * 16 + fr) * LDP + kk * 32 + quad * 8]);
      #pragma unroll
      for (int i = 0; i < 4; i++)
        #pragma unroll
        for (int j = 0; j < ACCJ; j++)
          acc[i][j] = __builtin_amdgcn_mfma_f32_16x16x32_bf16(afr[i], bfr[j], acc[i][j], 0, 0, 0);
    }
  }

  // Epilogue: C/D layout col=lane&15, row=quad*4+reg (verified m89/m91).
  #pragma unroll
  for (int i = 0; i < 4; i++) {
    const int mbase = m0 + wm + i * 16 + quad * 4;
    #pragma unroll
    for (int j = 0; j < ACCJ; j++) {
      const int n = wn + j * 16 + fr;
      const float bn = bias[n];
      #pragma unroll
      for (int r = 0; r < 4; r++) {
        const size_t m = (size_t)(mbase + r);
        float v = acc[i][j][r] + bn;
        if (RES) v += resid[m * (size_t)BN + n];
        if (CBF) ((unsigned short*)Cp)[m * (size_t)BN + n] = (unsigned short)f2bf(v);
        else     ((float*)Cp)[m * (size_t)BN + n] = v;
      }
    }
  }
}

// ------------------------------------------------------------- sampling ----
// 8 queries per block, 256 threads.
// Phase A: thread u -> one (qi,h,pt) tuple (8*8*4=256): softmax weight,
//          bilinear weights w00..w11 (validity folded), 4 corner element
//          offsets -> LDS. (Old code recomputed these 4x per dim-group.)
// Phase B: thread t -> (qi,h,dg): read 4 offset-quads + issue ALL 16 gather
//          loads back-to-back (block-uniform base -> saddr+voffset), then
//          read weights and accumulate with dword-pair bf16 unpack.
// launch_bounds(256,4): VGPR cap 128 (peak live ~115) -- same 4 waves/SIMD
// band as the 72-reg R0 version, but 2x the loads in flight. NO (256,8):
// that forced VGPR->32 and spilled 800MB of scratch (R4 post-mortem).
__global__ __launch_bounds__(256, 4)
void sample_k(const unsigned short* __restrict__ v, const float* __restrict__ p,
              const float* __restrict__ ref, unsigned short* __restrict__ o)
{
  const int t  = threadIdx.x;
  const int q0 = blockIdx.x * 8;
  __shared__ float sp[8][128];
  __shared__ float sref[16];
  __shared__ float sw[8][8][4][4];   // [qi][h][pt][corner] weights
  __shared__ int   so[8][8][4][4];   // [qi][h][pt][corner] element offsets
  {
    const float* pb = p + (size_t)q0 * 128;
    float* spf = &sp[0][0];
    *(f4*)(spf + t * 4) = *(const f4*)(pb + t * 4);
    if (t < 16) sref[t] = ref[(size_t)q0 * 2 + t];
  }
  __syncthreads();

  // ---- Phase A: one (qi,h,pt) per thread ----
  {
    const int qa = t >> 5;
    const int ha = (t >> 2) & 7;
    const int pa_ = t & 3;
    const float lg0 = sp[qa][64 + ha * 4 + 0], lg1 = sp[qa][64 + ha * 4 + 1];
    const float lg2 = sp[qa][64 + ha * 4 + 2], lg3 = sp[qa][64 + ha * 4 + 3];
    const float mx = fmaxf(fmaxf(lg0, lg1), fmaxf(lg2, lg3));
    const float e0 = __expf(lg0 - mx), e1 = __expf(lg1 - mx);
    const float e2 = __expf(lg2 - mx), e3 = __expf(lg3 - mx);
    const float inv = 1.f / (e0 + e1 + e2 + e3);
    const float a = ((pa_ == 0) ? e0 : (pa_ == 1) ? e1 : (pa_ == 2) ? e2 : e3) * inv;
    const float rx = sref[qa * 2], ry = sref[qa * 2 + 1];
    const float ox = sp[qa][ha * 8 + pa_ * 2], oy = sp[qa][ha * 8 + pa_ * 2 + 1];
    // px = loc_x*W - 0.5 with loc_x = rx + ox/W  ->  rx*W + ox - 0.5
    const float px = rx * 200.f + ox - 0.5f;
    const float py = ry * 200.f + oy - 0.5f;
    const float x0f = floorf(px), y0f = floorf(py);
    const int ix = (int)x0f, iy = (int)y0f;
    const float fx = px - x0f, fy = py - y0f;
    const float vx0 = (ix >= 0 && ix < GW) ? 1.f : 0.f;
    const float vx1 = (ix + 1 >= 0 && ix + 1 < GW) ? 1.f : 0.f;
    const float vy0 = (iy >= 0 && iy < GH) ? 1.f : 0.f;
    const float vy1 = (iy + 1 >= 0 && iy + 1 < GH) ? 1.f : 0.f;
    f4 wv;
    wv[0] = a * (1.f - fx) * (1.f - fy) * vx0 * vy0;
    wv[1] = a * fx * (1.f - fy) * vx1 * vy0;
    wv[2] = a * (1.f - fx) * fy * vx0 * vy1;
    wv[3] = a * fx * fy * vx1 * vy1;
    const int ix0c = min(max(ix, 0), GW - 1);
    const int ix1c = min(max(ix + 1, 0), GW - 1);
    const int iy0c = min(max(iy, 0), GH - 1);
    const int iy1c = min(max(iy + 1, 0), GH - 1);
    const int r0 = iy0c * (GW * 256);
    const int r1 = iy1c * (GW * 256);
    i4 ov;
    ov[0] = r0 + ix0c * 256;
    ov[1] = r0 + ix1c * 256;
    ov[2] = r1 + ix0c * 256;
    ov[3] = r1 + ix1c * 256;
    *(f4*)&sw[qa][ha][pa_][0] = wv;
    *(i4*)&so[qa][ha][pa_][0] = ov;
  }
  __syncthreads();

  // ---- Phase B: one (qi,h,dg) per thread; 16 loads in flight ----
  const int qi = t >> 5;
  const int h  = (t >> 2) & 7;
  const int dg = t & 3;
  const int q  = q0 + qi;
  // q0 multiple of 8 -> whole block same batch
  const unsigned short* vb = v + ((q0 >= 40000) ? (size_t)NVPIX * 256 : 0);
  const int cbase = h * 32 + dg * 8;

  i4 ofs[4];
  #pragma unroll
  for (int pt = 0; pt < 4; pt++) ofs[pt] = *(const i4*)&so[qi][h][pt][0];

  u4 g[16];
  #pragma unroll
  for (int pt = 0; pt < 4; pt++)
    #pragma unroll
    for (int c = 0; c < 4; c++)
      g[pt * 4 + c] = *(const u4*)(vb + (unsigned)(ofs[pt][c] + cbase));

  f4 wts[4];
  #pragma unroll
  for (int pt = 0; pt < 4; pt++) wts[pt] = *(const f4*)&sw[qi][h][pt][0];

  float acc[8];
  #pragma unroll
  for (int e = 0; e < 8; e++) acc[e] = 0.f;

  #pragma unroll
  for (int pt = 0; pt < 4; pt++) {
    #pragma unroll
    for (int c = 0; c < 4; c++) {
      const float wk = wts[pt][c];
      const u4 gu = g[pt * 4 + c];
      #pragma unroll
      for (int d = 0; d < 4; d++) {
        const unsigned u = gu[d];
        acc[2 * d]     += wk * asf(u << 16);           // low bf16
        acc[2 * d + 1] += wk * asf(u & 0xffff0000u);   // high bf16
      }
    }
  }

  s8 res;
  #pragma unroll
  for (int e = 0; e < 8; e++) res[e] = f2bf(acc[e]);
  *(s8*)(o + (size_t)q * 256 + cbase) = res;
}

// --------------------------------------------------------------- launch ----
extern "C" void kernel_launch(void* const* d_in, const int* in_sizes, int n_in,
                              void* d_out, int out_size, void* d_ws, size_t ws_size,
                              hipStream_t stream)
{
  const float* query = (const float*)d_in[0];
  const float* value = (const float*)d_in[1];
  const float* refp  = (const float*)d_in[2];
  // d_in[3] spatial_shapes: compile-time (200,200)
  const float* Wv    = (const float*)d_in[4];
  const float* bv    = (const float*)d_in[5];
  const float* Woff  = (const float*)d_in[6];
  const float* boff  = (const float*)d_in[7];
  const float* Wattn = (const float*)d_in[8];
  const float* battn = (const float*)d_in[9];
  const float* Wo    = (const float*)d_in[10];
  const float* bo    = (const float*)d_in[11];

  char* ws = (char*)d_ws;
  unsigned short* ws_v = (unsigned short*)ws;                  // 80000*256 bf16 = 40.96 MB
  float*          ws_p = (float*)(ws + 40960000);              // 80000*128 f32  = 40.96 MB
  unsigned short* ws_o = (unsigned short*)(ws + 81920000);     // 80000*256 bf16 = 40.96 MB
  unsigned short* Wv_t = (unsigned short*)(ws + 122880000);    // 256*256 bf16
  unsigned short* Wo_t = Wv_t + 65536;                         // 256*256 bf16
  unsigned short* Wp_t = Wo_t + 65536;                         // 128*256 bf16
  float*          bp   = (float*)(Wp_t + 32768);               // 128 f32

  hipLaunchKernelGGL(prep_k, dim3(641), dim3(256), 0, stream,
                     Wv, Wo, Woff, Wattn, boff, battn, Wv_t, Wo_t, Wp_t, bp);
  // v = value @ Wv + bv  -> bf16   (A read once: 128x256 tile per block)
  hipLaunchKernelGGL((gemm_k<0, 1, 0, 256>), dim3(625), dim3(512), 0, stream,
                     (const void*)value, Wv_t, bv, (const float*)nullptr, (void*)ws_v);
  // p = query @ [Woff|Wattn|0] + bp -> f32 (stride 128)
  hipLaunchKernelGGL((gemm_k<0, 0, 0, 128>), dim3(625), dim3(512), 0, stream,
                     (const void*)query, Wp_t, bp, (const float*)nullptr, (void*)ws_p);
  // sampling
  hipLaunchKernelGGL(sample_k, dim3(10000), dim3(256), 0, stream,
                     ws_v, ws_p, refp, ws_o);
  // out = samp @ Wo + bo + query -> f32
  hipLaunchKernelGGL((gemm_k<1, 0, 1, 256>), dim3(625), dim3(512), 0, stream,
                     (const void*)ws_o, Wo_t, bo, query, (void*)d_out);
}

// Round 4
// 328.612 us; speedup vs baseline: 1.9122x; 1.0388x over previous
//
#include <hip/hip_runtime.h>

// MS-Deformable Attention, MI355X gfx950.
// Pipeline: prep(weights->bf16,[N][K]) ; v=value@Wv (bf16 MFMA, out bf16)
//           p=query@[Woff|Wattn] (bf16 MFMA, out fp32, N padded to 128)
//           sampling (bilinear gather from bf16 v, out bf16)
//           out = samp@Wo + b + query (bf16 MFMA, fp32 out)
// R5: sample_k phase-split (weights/offsets via LDS), launch_bounds(256,4).
//     61us, but VGPR=40 -> compiler serialized the 16 gathers (latency-bound,
//     VALU 37% / BW 42%).
// R6: (a) sample_k: sched_barrier(0) fence after the 16-load cluster pins
//         all gathers in flight before the FMA section (VGPR ~110 < 128 cap).
//     (b) GEMM: 2-deep register pipeline + double-buffered LDS with raw
//         s_barrier + lgkmcnt(0) ONLY (no vmcnt drain at barriers). Loads for
//         chunk k+2 issued before compute(k) stay in flight across barriers;
//         storeAB consumes them one iter later (compiler emits counted vmcnt).
//         Kills the per-iter vmcnt(0) drain that capped HBM duty cycle.
//         buf0 holds chunks {0,2}, buf1 {1,3}; every buffer rewrite is one
//         lgkm-drained barrier after its last reader.

typedef float  f4  __attribute__((ext_vector_type(4)));
typedef float  fx4 __attribute__((ext_vector_type(4)));
typedef short  s8  __attribute__((ext_vector_type(8)));
typedef short  s4  __attribute__((ext_vector_type(4)));
typedef int    i4  __attribute__((ext_vector_type(4)));
typedef unsigned int u4 __attribute__((ext_vector_type(4)));

#define KDIM    256
#define NVPIX   40000
#define GH      200
#define GW      200
#define LDP     68          // LDS row pitch in shorts: 64 data + 4 pad -> conflict-free

__device__ __forceinline__ short f2bf(float f) {
  union { float f; unsigned u; } v; v.f = f;
  unsigned r = v.u + 0x7fffu + ((v.u >> 16) & 1u);   // round-to-nearest-even
  return (short)(r >> 16);
}
__device__ __forceinline__ float bf2f(unsigned short h) {
  union { unsigned u; float f; } v; v.u = ((unsigned)h) << 16; return v.f;
}
__device__ __forceinline__ float asf(unsigned u) {
  union { unsigned u; float f; } v; v.u = u; return v.f;
}

// ---------------------------------------------------------------- prep ----
__global__ void prep_k(const float* __restrict__ Wv, const float* __restrict__ Wo,
                       const float* __restrict__ Woff, const float* __restrict__ Wattn,
                       const float* __restrict__ boff, const float* __restrict__ battn,
                       unsigned short* __restrict__ Wv_t, unsigned short* __restrict__ Wo_t,
                       unsigned short* __restrict__ Wp_t, float* __restrict__ bp)
{
  int i = blockIdx.x * 256 + threadIdx.x;
  if (i < 65536) {
    int n = i >> 8, k = i & 255;
    Wv_t[i] = (unsigned short)f2bf(Wv[k * 256 + n]);
  } else if (i < 131072) {
    int j = i - 65536; int n = j >> 8, k = j & 255;
    Wo_t[j] = (unsigned short)f2bf(Wo[k * 256 + n]);
  } else if (i < 163840) {
    int j = i - 131072; int n = j >> 8, k = j & 255;
    float val = (n < 64) ? Woff[k * 64 + n] : ((n < 96) ? Wattn[k * 32 + (n - 64)] : 0.f);
    Wp_t[j] = (unsigned short)f2bf(val);
  } else if (i < 163968) {
    int j = i - 163840;
    bp[j] = (j < 64) ? boff[j] : ((j < 96) ? battn[j - 64] : 0.f);
  }
}

// ---------------------------------------------------------------- GEMM ----
// C[M,BN] = A[M,K=256] * B^T (Bt [BN][K] bf16) + bias (+resid). 128xBN tile,
// BK=64 (4 chunks), 8 waves (wave grid 2x4, per-wave 64x(BN/4)).
// 2-deep pipeline: reg sets s0/s1, LDS bufs b0/b1.
//   load(c0,s0); load(c1,s1); store(s0->b0); BAR;
//   load(c2,s0); compute(b0); store(s1->b1); BAR;
//   load(c3,s1); compute(b1); store(s0->b0); BAR;
//   compute(b0); store(s1->b1); BAR; compute(b1); epilogue.
// BAR = s_waitcnt lgkmcnt(0) + raw s_barrier: ds ops drained, global loads
// stay in flight across barriers (no vmcnt(0) drain).
template<int ABF, int CBF, int RES, int BN>
__global__ __launch_bounds__(512)
void gemm_k(const void* __restrict__ Ap, const unsigned short* __restrict__ Bt,
            const float* __restrict__ bias, const float* __restrict__ resid,
            void* __restrict__ Cp)
{
  constexpr int ACCJ = BN / 64;        // 4 (BN=256) or 2 (BN=128)
  constexpr int WN   = BN / 4;         // per-wave N extent: 64 or 32
  __shared__ short As[2][128 * LDP];
  __shared__ short Bs[2][BN * LDP];
  const int t  = threadIdx.x;
  const int m0 = blockIdx.x * 128;
  const int lane = t & 63;
  const int w  = t >> 6;               // 0..7
  const int wm = (w >> 2) * 64;        // 0,64
  const int wn = (w & 3) * WN;
  const int fr = lane & 15;
  const int quad = lane >> 4;

  fx4 acc[4][ACCJ];
  #pragma unroll
  for (int i = 0; i < 4; i++)
    #pragma unroll
    for (int j = 0; j < ACCJ; j++) { fx4 z = {0.f, 0.f, 0.f, 0.f}; acc[i][j] = z; }

  f4 paf[2][4];    // ABF=0: two prefetch sets, 128x64 f32 tile, 4 f4/thread
  s8 pab[2][2];    // ABF=1: two prefetch sets, 128x64 bf16 tile, 2 s8/thread
  s8 pb [2][ACCJ]; // B: two prefetch sets, BNx64 bf16, ACCJ s8/thread

  auto loadT = [&](int k0, int s) {
    if (ABF) {
      const unsigned short* base = (const unsigned short*)Ap + (size_t)m0 * KDIM + k0;
      #pragma unroll
      for (int j = 0; j < 2; j++) {
        int id = t + j * 512;                   // coalesced
        pab[s][j] = *(const s8*)(base + (size_t)(id >> 3) * KDIM + (id & 7) * 8);
      }
    } else {
      const float* base = (const float*)Ap + (size_t)m0 * KDIM + k0;
      #pragma unroll
      for (int j = 0; j < 4; j++) {
        int id = t + j * 512;                   // coalesced
        paf[s][j] = *(const f4*)(base + (size_t)(id >> 4) * KDIM + (id & 15) * 4);
      }
    }
    const unsigned short* bbase = Bt + k0;
    #pragma unroll
    for (int j = 0; j < ACCJ; j++) {
      int id = t + j * 512;
      pb[s][j] = *(const s8*)(bbase + (size_t)(id >> 3) * KDIM + (id & 7) * 8);
    }
  };
  auto storeT = [&](int buf, int s) {
    if (ABF) {
      #pragma unroll
      for (int j = 0; j < 2; j++) {
        int id = t + j * 512;
        *(s8*)(&As[buf][(id >> 3) * LDP + (id & 7) * 8]) = pab[s][j];
      }
    } else {
      #pragma unroll
      for (int j = 0; j < 4; j++) {
        int id = t + j * 512;
        s4 c;
        #pragma unroll
        for (int e = 0; e < 4; e++) c[e] = f2bf(paf[s][j][e]);
        *(s4*)(&As[buf][(id >> 4) * LDP + (id & 15) * 4]) = c;   // ds_write_b64
      }
    }
    #pragma unroll
    for (int j = 0; j < ACCJ; j++) {
      int id = t + j * 512;
      *(s8*)(&Bs[buf][(id >> 3) * LDP + (id & 7) * 8]) = pb[s][j];  // ds_write_b128
    }
  };
  auto compute = [&](int buf) {
    #pragma unroll
    for (int kk = 0; kk < 2; kk++) {
      s8 afr[4], bfr[ACCJ];
      #pragma unroll
      for (int i = 0; i < 4; i++)
        afr[i] = *(const s8*)(&As[buf][(wm + i * 16 + fr) * LDP + kk * 32 + quad * 8]);
      #pragma unroll
      for (int j = 0; j < ACCJ; j++)
        bfr[j] = *(const s8*)(&Bs[buf][(wn + j * 16 + fr) * LDP + kk * 32 + quad * 8]);
      #pragma unroll
      for (int i = 0; i < 4; i++)
        #pragma unroll
        for (int j = 0; j < ACCJ; j++)
          acc[i][j] = __builtin_amdgcn_mfma_f32_16x16x32_bf16(afr[i], bfr[j], acc[i][j], 0, 0, 0);
    }
  };

  // BAR: drain LDS ops only; global loads remain in flight across barrier.
#define GBAR() do { asm volatile("s_waitcnt lgkmcnt(0)" ::: "memory"); \
                    __builtin_amdgcn_s_barrier(); } while (0)

  loadT(0, 0);
  loadT(64, 1);
  storeT(0, 0);        // waits set0 loads only (set1 still flying)
  GBAR();
  loadT(128, 0);       // chunk 2 in flight across next barrier
  compute(0);          // chunk 0
  storeT(1, 1);        // waits set1 (landed long ago)
  GBAR();
  loadT(192, 1);       // chunk 3 in flight
  compute(1);          // chunk 1
  storeT(0, 0);        // chunk 2 (hidden under compute above)
  GBAR();
  compute(0);          // chunk 2
  storeT(1, 1);        // chunk 3
  GBAR();
  compute(1);          // chunk 3
#undef GBAR

  // Epilogue: C/D layout col=lane&15, row=quad*4+reg (verified m89/m91).
  #pragma unroll
  for (int i = 0; i < 4; i++) {
    const int mbase = m0 + wm + i * 16 + quad * 4;
    #pragma unroll
    for (int j = 0; j < ACCJ; j++) {
      const int n = wn + j * 16 + fr;
      const float bn = bias[n];
      #pragma unroll
      for (int r = 0; r < 4; r++) {
        const size_t m = (size_t)(mbase + r);
        float v = acc[i][j][r] + bn;
        if (RES) v += resid[m * (size_t)BN + n];
        if (CBF) ((unsigned short*)Cp)[m * (size_t)BN + n] = (unsigned short)f2bf(v);
        else     ((float*)Cp)[m * (size_t)BN + n] = v;
      }
    }
  }
}

// ------------------------------------------------------------- sampling ----
// 8 queries per block, 256 threads.
// Phase A: thread u -> one (qi,h,pt) tuple: softmax weight, bilinear weights,
//          4 corner element offsets -> LDS.
// Phase B: thread t -> (qi,h,dg): issue ALL 16 gather loads, then
//          sched_barrier(0) pins them in flight (R5: compiler had serialized
//          them to save VGPR -> VGPR=40, latency-bound), then FMA.
// launch_bounds(256,4): VGPR cap 128 (peak live ~115, no spill).
__global__ __launch_bounds__(256, 4)
void sample_k(const unsigned short* __restrict__ v, const float* __restrict__ p,
              const float* __restrict__ ref, unsigned short* __restrict__ o)
{
  const int t  = threadIdx.x;
  const int q0 = blockIdx.x * 8;
  __shared__ float sp[8][128];
  __shared__ float sref[16];
  __shared__ float sw[8][8][4][4];   // [qi][h][pt][corner] weights
  __shared__ int   so[8][8][4][4];   // [qi][h][pt][corner] element offsets
  {
    const float* pb = p + (size_t)q0 * 128;
    float* spf = &sp[0][0];
    *(f4*)(spf + t * 4) = *(const f4*)(pb + t * 4);
    if (t < 16) sref[t] = ref[(size_t)q0 * 2 + t];
  }
  __syncthreads();

  // ---- Phase A: one (qi,h,pt) per thread ----
  {
    const int qa = t >> 5;
    const int ha = (t >> 2) & 7;
    const int pa_ = t & 3;
    const float lg0 = sp[qa][64 + ha * 4 + 0], lg1 = sp[qa][64 + ha * 4 + 1];
    const float lg2 = sp[qa][64 + ha * 4 + 2], lg3 = sp[qa][64 + ha * 4 + 3];
    const float mx = fmaxf(fmaxf(lg0, lg1), fmaxf(lg2, lg3));
    const float e0 = __expf(lg0 - mx), e1 = __expf(lg1 - mx);
    const float e2 = __expf(lg2 - mx), e3 = __expf(lg3 - mx);
    const float inv = 1.f / (e0 + e1 + e2 + e3);
    const float a = ((pa_ == 0) ? e0 : (pa_ == 1) ? e1 : (pa_ == 2) ? e2 : e3) * inv;
    const float rx = sref[qa * 2], ry = sref[qa * 2 + 1];
    const float ox = sp[qa][ha * 8 + pa_ * 2], oy = sp[qa][ha * 8 + pa_ * 2 + 1];
    // px = loc_x*W - 0.5 with loc_x = rx + ox/W  ->  rx*W + ox - 0.5
    const float px = rx * 200.f + ox - 0.5f;
    const float py = ry * 200.f + oy - 0.5f;
    const float x0f = floorf(px), y0f = floorf(py);
    const int ix = (int)x0f, iy = (int)y0f;
    const float fx = px - x0f, fy = py - y0f;
    const float vx0 = (ix >= 0 && ix < GW) ? 1.f : 0.f;
    const float vx1 = (ix + 1 >= 0 && ix + 1 < GW) ? 1.f : 0.f;
    const float vy0 = (iy >= 0 && iy < GH) ? 1.f : 0.f;
    const float vy1 = (iy + 1 >= 0 && iy + 1 < GH) ? 1.f : 0.f;
    f4 wv;
    wv[0] = a * (1.f - fx) * (1.f - fy) * vx0 * vy0;
    wv[1] = a * fx * (1.f - fy) * vx1 * vy0;
    wv[2] = a * (1.f - fx) * fy * vx0 * vy1;
    wv[3] = a * fx * fy * vx1 * vy1;
    const int ix0c = min(max(ix, 0), GW - 1);
    const int ix1c = min(max(ix + 1, 0), GW - 1);
    const int iy0c = min(max(iy, 0), GH - 1);
    const int iy1c = min(max(iy + 1, 0), GH - 1);
    const int r0 = iy0c * (GW * 256);
    const int r1 = iy1c * (GW * 256);
    i4 ov;
    ov[0] = r0 + ix0c * 256;
    ov[1] = r0 + ix1c * 256;
    ov[2] = r1 + ix0c * 256;
    ov[3] = r1 + ix1c * 256;
    *(f4*)&sw[qa][ha][pa_][0] = wv;
    *(i4*)&so[qa][ha][pa_][0] = ov;
  }
  __syncthreads();

  // ---- Phase B: one (qi,h,dg) per thread; 16 loads pinned in flight ----
  const int qi = t >> 5;
  const int h  = (t >> 2) & 7;
  const int dg = t & 3;
  const int q  = q0 + qi;
  // q0 multiple of 8 -> whole block same batch
  const unsigned short* vb = v + ((q0 >= 40000) ? (size_t)NVPIX * 256 : 0);
  const int cbase = h * 32 + dg * 8;

  i4 ofs[4];
  #pragma unroll
  for (int pt = 0; pt < 4; pt++) ofs[pt] = *(const i4*)&so[qi][h][pt][0];

  u4 g[16];
  #pragma unroll
  for (int pt = 0; pt < 4; pt++)
    #pragma unroll
    for (int c = 0; c < 4; c++)
      g[pt * 4 + c] = *(const u4*)(vb + (unsigned)(ofs[pt][c] + cbase));

  // Pin: nothing below may be scheduled above this point -> all 16 gathers
  // are issued back-to-back before the first FMA consumes any of them.
  __builtin_amdgcn_sched_barrier(0);

  f4 wts[4];
  #pragma unroll
  for (int pt = 0; pt < 4; pt++) wts[pt] = *(const f4*)&sw[qi][h][pt][0];

  float acc[8];
  #pragma unroll
  for (int e = 0; e < 8; e++) acc[e] = 0.f;

  #pragma unroll
  for (int pt = 0; pt < 4; pt++) {
    #pragma unroll
    for (int c = 0; c < 4; c++) {
      const float wk = wts[pt][c];
      const u4 gu = g[pt * 4 + c];
      #pragma unroll
      for (int d = 0; d < 4; d++) {
        const unsigned u = gu[d];
        acc[2 * d]     += wk * asf(u << 16);           // low bf16
        acc[2 * d + 1] += wk * asf(u & 0xffff0000u);   // high bf16
      }
    }
  }

  s8 res;
  #pragma unroll
  for (int e = 0; e < 8; e++) res[e] = f2bf(acc[e]);
  *(s8*)(o + (size_t)q * 256 + cbase) = res;
}

// --------------------------------------------------------------- launch ----
extern "C" void kernel_launch(void* const* d_in, const int* in_sizes, int n_in,
                              void* d_out, int out_size, void* d_ws, size_t ws_size,
                              hipStream_t stream)
{
  const float* query = (const float*)d_in[0];
  const float* value = (const float*)d_in[1];
  const float* refp  = (const float*)d_in[2];
  // d_in[3] spatial_shapes: compile-time (200,200)
  const float* Wv    = (const float*)d_in[4];
  const float* bv    = (const float*)d_in[5];
  const float* Woff  = (const float*)d_in[6];
  const float* boff  = (const float*)d_in[7];
  const float* Wattn = (const float*)d_in[8];
  const float* battn = (const float*)d_in[9];
  const float* Wo    = (const float*)d_in[10];
  const float* bo    = (const float*)d_in[11];

  char* ws = (char*)d_ws;
  unsigned short* ws_v = (unsigned short*)ws;                  // 80000*256 bf16 = 40.96 MB
  float*          ws_p = (float*)(ws + 40960000);              // 80000*128 f32  = 40.96 MB
  unsigned short* ws_o = (unsigned short*)(ws + 81920000);     // 80000*256 bf16 = 40.96 MB
  unsigned short* Wv_t = (unsigned short*)(ws + 122880000);    // 256*256 bf16
  unsigned short* Wo_t = Wv_t + 65536;                         // 256*256 bf16
  unsigned short* Wp_t = Wo_t + 65536;                         // 128*256 bf16
  float*          bp   = (float*)(Wp_t + 32768);               // 128 f32

  hipLaunchKernelGGL(prep_k, dim3(641), dim3(256), 0, stream,
                     Wv, Wo, Woff, Wattn, boff, battn, Wv_t, Wo_t, Wp_t, bp);
  // v = value @ Wv + bv  -> bf16   (A read once: 128x256 tile per block)
  hipLaunchKernelGGL((gemm_k<0, 1, 0, 256>), dim3(625), dim3(512), 0, stream,
                     (const void*)value, Wv_t, bv, (const float*)nullptr, (void*)ws_v);
  // p = query @ [Woff|Wattn|0] + bp -> f32 (stride 128)
  hipLaunchKernelGGL((gemm_k<0, 0, 0, 128>), dim3(625), dim3(512), 0, stream,
                     (const void*)query, Wp_t, bp, (const float*)nullptr, (void*)ws_p);
  // sampling
  hipLaunchKernelGGL(sample_k, dim3(10000), dim3(256), 0, stream,
                     ws_v, ws_p, refp, ws_o);
  // out = samp @ Wo + bo + query -> f32
  hipLaunchKernelGGL((gemm_k<1, 0, 1, 256>), dim3(625), dim3(512), 0, stream,
                     (const void*)ws_o, Wo_t, bo, query, (void*)d_out);
}